// Round 10
// baseline (158.014 us; speedup 1.0000x reference)
//
#include <hip/hip_runtime.h>
#include <hip/hip_bf16.h>

#define NN 50000
#define EE 800000
#define HC 128
#define GG 64

#define NBLK 256
#define CHUNK (EE / NBLK)          // 3125
#define NBUCK ((NN + 63) >> 6)     // 782 coarse buckets (64 nodes each)
#define NTOT (NBUCK * NBLK)        // 200192 count-matrix entries
#define NSB ((NTOT + 1023) / 1024) // 196 scan blocks
#define ECAP 2048                  // per-bucket edge capacity (mean ~1023, sd ~32)

typedef __attribute__((ext_vector_type(8))) short bf16x8;
typedef __attribute__((ext_vector_type(4))) float f32x4;
typedef _Float16 hv2 __attribute__((ext_vector_type(2)));

// ---- DPP 16-lane rotate-reduction: every lane ends with its 16-group sum ----
__device__ __forceinline__ float dpp4_rorsum(float t) {
  t += __int_as_float(__builtin_amdgcn_update_dpp(__float_as_int(t), __float_as_int(t), 0x121, 0xf, 0xf, false));
  t += __int_as_float(__builtin_amdgcn_update_dpp(__float_as_int(t), __float_as_int(t), 0x122, 0xf, 0xf, false));
  t += __int_as_float(__builtin_amdgcn_update_dpp(__float_as_int(t), __float_as_int(t), 0x124, 0xf, 0xf, false));
  t += __int_as_float(__builtin_amdgcn_update_dpp(__float_as_int(t), __float_as_int(t), 0x128, 0xf, 0xf, false));
  return t;
}

__device__ __forceinline__ unsigned pkbf(float lo, float hi) {
  __hip_bfloat162 h = __float22bfloat162_rn(float2{lo, hi});  // x -> low 16 bits
  return *reinterpret_cast<unsigned*>(&h);
}

// two edges, packed-f16 source rows: w holds channels (2*lane, 2*lane+1)
__device__ __forceinline__ void proc2h(unsigned wa, unsigned wb, hv2 att2, hv2 xr2,
                                       float& s, float& a0, float& a1) {
  hv2 va = __builtin_bit_cast(hv2, wa);
  hv2 vb = __builtin_bit_cast(hv2, wb);
  hv2 ya = va + xr2, yb = vb + xr2;
  hv2 la = __builtin_elementwise_max(ya, ya * (_Float16)0.2f);  // leaky_relu
  hv2 lb = __builtin_elementwise_max(yb, yb * (_Float16)0.2f);
  float ta = __builtin_amdgcn_fdot2(la, att2, 0.f, false);
  float tb = __builtin_amdgcn_fdot2(lb, att2, 0.f, false);
  float pa = __builtin_amdgcn_exp2f(dpp4_rorsum(ta));  // att pre-scaled by log2(e)
  float pb = __builtin_amdgcn_exp2f(dpp4_rorsum(tb));
  s += pa + pb;
  a0 = fmaf(pa, (float)va.x, a0); a1 = fmaf(pa, (float)va.y, a1);
  a0 = fmaf(pb, (float)vb.x, a0); a1 = fmaf(pb, (float)vb.y, a1);
}

// ---------------- W transpose+convert: Wtb[c][k] bf16, c<128 = Wl, else Wr ----------------
__global__ __launch_bounds__(128) void prep_w(const float* __restrict__ Wl,
                                              const float* __restrict__ Wr,
                                              short* __restrict__ Wtb) {
  int c = blockIdx.x;           // 0..255
  int k = threadIdx.x;          // 0..127
  const float* W = (c < 128) ? Wl : Wr;
  float v = W[k * 128 + (c & 127)];
  Wtb[c * 128 + k] = (short)(pkbf(v, 0.f) & 0xFFFF);
}

// ---------------- GEMM (MFMA bf16): one x-tile stage -> BOTH xl and xr ----------------
__global__ __launch_bounds__(256) void gemm_xw(
    const float* __restrict__ x, const short* __restrict__ Wtb,
    _Float16* __restrict__ xlh, _Float16* __restrict__ xrh)
{
  __shared__ short xs[128 * 136];
  const int t = threadIdx.x;
  const int rowbase = blockIdx.x * 128;
#pragma unroll
  for (int i = 0; i < 16; ++i) {
    int fi = i * 256 + t;            // 4096 float4 per tile
    int row = fi >> 5, k4 = fi & 31;
    int ar = rowbase + row; if (ar >= NN) ar = NN - 1;
    float4 v = *(const float4*)(x + (size_t)ar * 128 + k4 * 4);
    uint2 p = { pkbf(v.x, v.y), pkbf(v.z, v.w) };
    *(uint2*)&xs[row * 136 + k4 * 4] = p;
  }
  __syncthreads();
  const int w = t >> 6, l = t & 63;
  const int lo16 = l & 15, hi = l >> 4;
  f32x4 accL[2][8], accR[2][8];
#pragma unroll
  for (int rf = 0; rf < 2; ++rf)
#pragma unroll
    for (int cf = 0; cf < 8; ++cf) {
      accL[rf][cf] = f32x4{0.f, 0.f, 0.f, 0.f};
      accR[rf][cf] = f32x4{0.f, 0.f, 0.f, 0.f};
    }

  const short* asrc0 = &xs[(w * 32 + lo16) * 136 + hi * 8];
  const short* asrc1 = asrc0 + 16 * 136;
#pragma unroll
  for (int ks = 0; ks < 4; ++ks) {
    bf16x8 a0 = *(const bf16x8*)(asrc0 + ks * 32);
    bf16x8 a1 = *(const bf16x8*)(asrc1 + ks * 32);
#pragma unroll
    for (int cf = 0; cf < 8; ++cf) {
      const short* bp = &Wtb[(cf * 16 + lo16) * 128 + ks * 32 + hi * 8];
      bf16x8 bL = *(const bf16x8*)bp;
      bf16x8 bR = *(const bf16x8*)(bp + 128 * 128);
      accL[0][cf] = __builtin_amdgcn_mfma_f32_16x16x32_bf16(a0, bL, accL[0][cf], 0, 0, 0);
      accL[1][cf] = __builtin_amdgcn_mfma_f32_16x16x32_bf16(a1, bL, accL[1][cf], 0, 0, 0);
      accR[0][cf] = __builtin_amdgcn_mfma_f32_16x16x32_bf16(a0, bR, accR[0][cf], 0, 0, 0);
      accR[1][cf] = __builtin_amdgcn_mfma_f32_16x16x32_bf16(a1, bR, accR[1][cf], 0, 0, 0);
    }
  }
  // D layout: col=l&15, row=(l>>4)*4+reg
#pragma unroll
  for (int rf = 0; rf < 2; ++rf)
#pragma unroll
    for (int cf = 0; cf < 8; ++cf)
#pragma unroll
      for (int r = 0; r < 4; ++r) {
        int row = rowbase + w * 32 + rf * 16 + hi * 4 + r;
        if (row < NN) {
          int col = cf * 16 + lo16;
          xlh[(size_t)row * 128 + col] = (_Float16)accL[rf][cf][r];
          xrh[(size_t)row * 128 + col] = (_Float16)accR[rf][cf][r];
        }
      }
}

// ---------------- CSR build: atomic-free two-level counting sort ----------------
__global__ __launch_bounds__(256) void hist_coarse(const int* __restrict__ ei,
                                                   int* __restrict__ H2) {
  __shared__ int h[NBUCK];
  int t = threadIdx.x, blk = blockIdx.x;
  for (int b = t; b < NBUCK; b += 256) h[b] = 0;
  __syncthreads();
  int e0 = blk * CHUNK;
  for (int i = t; i < CHUNK; i += 256) {
    int d = ei[EE + e0 + i];
    atomicAdd(&h[d >> 6], 1);      // LDS atomic
  }
  __syncthreads();
  for (int b = t; b < NBUCK; b += 256) H2[blk * NBUCK + b] = h[b];
}

// exclusive scan over bucket-major logical order (L = bucket*NBLK + blk)
__global__ __launch_bounds__(256) void scanA(const int* __restrict__ H2,
                                             int* __restrict__ PS, int* __restrict__ bsum) {
  __shared__ int tmp[256];
  int t = threadIdx.x;
  int base = blockIdx.x * 1024 + t * 4;
  int v[4], local = 0;
#pragma unroll
  for (int j = 0; j < 4; ++j) {
    int L = base + j;
    v[j] = (L < NTOT) ? H2[(L % NBLK) * NBUCK + (L / NBLK)] : 0;
    local += v[j];
  }
  tmp[t] = local; __syncthreads();
  for (int off = 1; off < 256; off <<= 1) {
    int xv = (t >= off) ? tmp[t - off] : 0; __syncthreads();
    tmp[t] += xv; __syncthreads();
  }
  int excl = tmp[t] - local;
#pragma unroll
  for (int j = 0; j < 4; ++j) { int L = base + j; if (L < NTOT) PS[L] = excl; excl += v[j]; }
  if (t == 255) bsum[blockIdx.x] = tmp[255];
}

__global__ void scanB(int* __restrict__ bsum) {
  __shared__ int tmp[256];
  int t = threadIdx.x;
  int v = (t < NSB) ? bsum[t] : 0;
  tmp[t] = v; __syncthreads();
  for (int off = 1; off < 256; off <<= 1) {
    int xv = (t >= off) ? tmp[t - off] : 0; __syncthreads();
    tmp[t] += xv; __syncthreads();
  }
  if (t < NSB) bsum[t] = tmp[t] - v;
}

// scatter into per-(bucket,block) sequential runs; pack src|fine<<16
__global__ __launch_bounds__(256) void scatter_coarse(const int* __restrict__ ei,
                                                      const int* __restrict__ PS,
                                                      const int* __restrict__ bsum,
                                                      int* __restrict__ ec) {
  __shared__ int colbase[NBUCK];
  __shared__ int cur[NBUCK];
  int t = threadIdx.x, blk = blockIdx.x;
  for (int b = t; b < NBUCK; b += 256) {
    int L = b * NBLK + blk;
    colbase[b] = PS[L] + bsum[L >> 10];
    cur[b] = 0;
  }
  __syncthreads();
  int e0 = blk * CHUNK;
  for (int i = t; i < CHUNK; i += 256) {
    int d = ei[EE + e0 + i], s = ei[e0 + i];
    int b = d >> 6;
    int r = atomicAdd(&cur[b], 1);  // LDS atomic
    ec[colbase[b] + r] = s | ((d & 63) << 16);
  }
}

// per-bucket fine sort (64 nodes), inject self-loops, emit rs + coalesced csr
__global__ __launch_bounds__(256) void fine_sort(const int* __restrict__ PS,
                                                 const int* __restrict__ bsum,
                                                 const int* __restrict__ ec,
                                                 int* __restrict__ rs, int* __restrict__ csr) {
  __shared__ int lbuf[ECAP];
  __shared__ int outb[ECAP + 64];
  __shared__ int fh[64], sexcl[65], cur2[64];
  int t = threadIdx.x, b = blockIdx.x;
  int L0 = b * NBLK;
  int start = PS[L0] + bsum[L0 >> 10];
  int end;
  if (b + 1 < NBUCK) { int L1 = (b + 1) * NBLK; end = PS[L1] + bsum[L1 >> 10]; }
  else end = EE;
  int node0 = b << 6;
  int nl = NN - node0; if (nl > 64) nl = 64;
  int cnt = end - start; if (cnt > ECAP) cnt = ECAP;
  if (t < 64) { fh[t] = 0; cur2[t] = 0; }
  __syncthreads();
  for (int i = t; i < cnt; i += 256) {
    int p = ec[start + i];
    lbuf[i] = p;
    atomicAdd(&fh[(p >> 16) & 63], 1);
  }
  __syncthreads();
  if (t < 64) {   // wave 0: inclusive shfl-scan of 64 bins (+1 self-loop per live node)
    int val = fh[t] + (t < nl ? 1 : 0);
    int w = val;
    for (int off = 1; off < 64; off <<= 1) {
      int u = __shfl_up(w, off);
      if (t >= off) w += u;
    }
    sexcl[t] = w - val;
    if (t == 63) sexcl[64] = w;
  }
  __syncthreads();
  int base = start + node0;   // node0 == number of self-loops in earlier buckets
  if (t <= nl) rs[node0 + t] = base + sexcl[t];
  if (t < nl) {
    int r = atomicAdd(&cur2[t], 1);
    outb[sexcl[t] + r] = node0 + t;              // self-loop src = node itself
  }
  for (int i = t; i < cnt; i += 256) {
    int p = lbuf[i];
    int f = (p >> 16) & 63;
    int r = atomicAdd(&cur2[f], 1);
    outb[sexcl[f] + r] = p & 0xFFFF;
  }
  __syncthreads();
  int tot = cnt + nl;
  for (int i = t; i < tot; i += 256) csr[base + i] = outb[i];
}

// ---------------- main aggregation: one wave per node, f16-packed gather ----------------
__global__ __launch_bounds__(256) void gat_agg(
    const unsigned* __restrict__ xlu, const unsigned* __restrict__ xru,
    const int* __restrict__ rs, const int* __restrict__ csr,
    const float* __restrict__ att, const float* __restrict__ bias,
    float* __restrict__ outn)
{
  int wid = threadIdx.x >> 6, lane = threadIdx.x & 63;
  int n = blockIdx.x * 4 + wid;
  if (n >= NN) return;
  hv2 xr2 = __builtin_bit_cast(hv2, xru[n * 64 + lane]);
  float2 at2 = ((const float2*)att)[lane];
  const float LOG2E = 1.4426950408889634f;
  hv2 att2;
  att2.x = (_Float16)(at2.x * LOG2E);
  att2.y = (_Float16)(at2.y * LOG2E);
  float s = 0.f, a0 = 0.f, a1 = 0.f;

  int jbeg = rs[n], jend = rs[n + 1];
  for (int j0 = jbeg; j0 < jend; j0 += 64) {
    int cnt = jend - j0; if (cnt > 64) cnt = 64;
    int sj = csr[j0 + (lane < cnt ? lane : cnt - 1)];
    int base = 0;
    for (; base + 8 <= cnt; base += 8) {
      // uniform (SGPR) row pointers -> global_load s[base]+v_lane, no per-load VALU
      const unsigned* p0 = xlu + 64 * __builtin_amdgcn_readlane(sj, base + 0);
      const unsigned* p1 = xlu + 64 * __builtin_amdgcn_readlane(sj, base + 1);
      const unsigned* p2 = xlu + 64 * __builtin_amdgcn_readlane(sj, base + 2);
      const unsigned* p3 = xlu + 64 * __builtin_amdgcn_readlane(sj, base + 3);
      const unsigned* p4 = xlu + 64 * __builtin_amdgcn_readlane(sj, base + 4);
      const unsigned* p5 = xlu + 64 * __builtin_amdgcn_readlane(sj, base + 5);
      const unsigned* p6 = xlu + 64 * __builtin_amdgcn_readlane(sj, base + 6);
      const unsigned* p7 = xlu + 64 * __builtin_amdgcn_readlane(sj, base + 7);
      unsigned w0 = p0[lane];
      unsigned w1 = p1[lane];
      unsigned w2 = p2[lane];
      unsigned w3 = p3[lane];
      unsigned w4 = p4[lane];
      unsigned w5 = p5[lane];
      unsigned w6 = p6[lane];
      unsigned w7 = p7[lane];
      proc2h(w0, w1, att2, xr2, s, a0, a1);
      proc2h(w2, w3, att2, xr2, s, a0, a1);
      proc2h(w4, w5, att2, xr2, s, a0, a1);
      proc2h(w6, w7, att2, xr2, s, a0, a1);
    }
    for (; base + 2 <= cnt; base += 2) {
      const unsigned* p0 = xlu + 64 * __builtin_amdgcn_readlane(sj, base + 0);
      const unsigned* p1 = xlu + 64 * __builtin_amdgcn_readlane(sj, base + 1);
      unsigned w0 = p0[lane];
      unsigned w1 = p1[lane];
      proc2h(w0, w1, att2, xr2, s, a0, a1);
    }
    if (base < cnt) {
      const unsigned* p0 = xlu + 64 * __builtin_amdgcn_readlane(sj, base);
      unsigned w0 = p0[lane];
      hv2 va = __builtin_bit_cast(hv2, w0);
      hv2 ya = va + xr2;
      hv2 la = __builtin_elementwise_max(ya, ya * (_Float16)0.2f);
      float t = __builtin_amdgcn_fdot2(la, att2, 0.f, false);
      float p = __builtin_amdgcn_exp2f(dpp4_rorsum(t));
      s += p;
      a0 = fmaf(p, (float)va.x, a0); a1 = fmaf(p, (float)va.y, a1);
    }
  }
  float inv = 1.f / s;
  float2 bi = ((const float2*)bias)[lane];
  float2 o;
  o.x = fmaxf(fmaf(a0, inv, bi.x), 0.f);
  o.y = fmaxf(fmaf(a1, inv, bi.y), 0.f);
  ((float2*)outn)[n * 64 + lane] = o;
}

// ---------------- pooling ----------------
__global__ __launch_bounds__(128) void pool_max(const float* __restrict__ outn,
                                                const int* __restrict__ batch,
                                                unsigned int* __restrict__ pooled) {
  int c = threadIdx.x;
  int n0 = blockIdx.x * 128;
  int nend = n0 + 128; if (nend > NN) nend = NN;
  int curg = batch[n0];
  float mx = 0.f;
#pragma unroll 4
  for (int n = n0; n < nend; ++n) {
    int g = batch[n];
    if (g != curg) {
      atomicMax(&pooled[curg * HC + c], __float_as_uint(mx));
      mx = 0.f; curg = g;
    }
    mx = fmaxf(mx, outn[(size_t)n * HC + c]);
  }
  atomicMax(&pooled[curg * HC + c], __float_as_uint(mx));
}

// ---------------- MLP head ----------------
__global__ __launch_bounds__(128) void mlp_out(const unsigned int* __restrict__ pooled,
                                               const float* __restrict__ W,
                                               const float* __restrict__ b,
                                               float* __restrict__ out) {
  __shared__ float p[128];
  int g = blockIdx.x, j = threadIdx.x;
  p[j] = __uint_as_float(pooled[g * HC + j]);
  __syncthreads();
  float acc = b[j];
#pragma unroll 8
  for (int k = 0; k < 128; ++k) acc = fmaf(p[k], W[k * 128 + j], acc);
  out[g * HC + j] = fmaxf(acc, 0.f);
}

extern "C" void kernel_launch(void* const* d_in, const int* in_sizes, int n_in,
                              void* d_out, int out_size, void* d_ws, size_t ws_size,
                              hipStream_t stream) {
  const float* x    = (const float*)d_in[0];
  const int*   ei   = (const int*)d_in[1];
  const int*   batch= (const int*)d_in[2];
  const float* Wl   = (const float*)d_in[4];
  const float* Wr   = (const float*)d_in[5];
  const float* att  = (const float*)d_in[6];
  const float* bias = (const float*)d_in[7];
  const float* Wm   = (const float*)d_in[8];
  const float* bm   = (const float*)d_in[9];

  char* ws = (char*)d_ws;
  size_t off = 0;
  auto alloc = [&](size_t bytes) { void* p = ws + off; off += (bytes + 255) & ~size_t(255); return p; };
  unsigned* xlu  = (unsigned*)alloc((size_t)NN * 64 * 4);   // f16-packed xl (12.8 MB)
  unsigned* xru  = (unsigned*)alloc((size_t)NN * 64 * 4);   // f16-packed xr (12.8 MB)
  float* outn    = (float*)alloc((size_t)NN * HC * 4);
  int*   rs      = (int*)alloc((size_t)(NN + 1) * 4);
  int*   csr     = (int*)alloc((size_t)(EE + NN) * 4);
  int*   bsum    = (int*)alloc(NSB * 4);
  short* Wtb     = (short*)alloc((size_t)256 * 128 * 2);    // bf16 W^T [col][k]
  unsigned int* pooled = (unsigned int*)alloc((size_t)GG * HC * 4);
  // scratch aliased into outn (dead before gat_agg writes outn):
  int* ec = (int*)outn;                                      // 3.2 MB coarse-sorted edges
  int* H2 = (int*)((char*)outn + (size_t)4 * 1024 * 1024);   // 800 KB count matrix
  int* PS = (int*)((char*)outn + (size_t)6 * 1024 * 1024);   // 800 KB scanned positions

  (void)hipMemsetAsync(pooled, 0, (size_t)GG * HC * 4, stream);

  prep_w<<<256, 128, 0, stream>>>(Wl, Wr, Wtb);
  gemm_xw<<<(NN + 127) / 128, 256, 0, stream>>>(x, Wtb, (_Float16*)xlu, (_Float16*)xru);
  hist_coarse<<<NBLK, 256, 0, stream>>>(ei, H2);
  scanA<<<NSB, 256, 0, stream>>>(H2, PS, bsum);
  scanB<<<1, 256, 0, stream>>>(bsum);
  scatter_coarse<<<NBLK, 256, 0, stream>>>(ei, PS, bsum, ec);
  fine_sort<<<NBUCK, 256, 0, stream>>>(PS, bsum, ec, rs, csr);
  gat_agg<<<NN / 4, 256, 0, stream>>>(xlu, xru, rs, csr, att, bias, outn);
  pool_max<<<(NN + 127) / 128, 128, 0, stream>>>(outn, batch, pooled);
  mlp_out<<<GG, 128, 0, stream>>>(pooled, Wm, bm, (float*)d_out);
}

// Round 11
// 150.103 us; speedup vs baseline: 1.0527x; 1.0527x over previous
//
#include <hip/hip_runtime.h>
#include <hip/hip_bf16.h>

#define NN 50000
#define EE 800000
#define HC 128
#define GG 64

#define NBLK 256
#define CHUNK (EE / NBLK)          // 3125
#define NBUCK ((NN + 63) >> 6)     // 782 coarse buckets (64 nodes each)
#define NTOT (NBUCK * NBLK)        // 200192 count-matrix entries
#define NSB ((NTOT + 1023) / 1024) // 196 scan blocks
#define ECAP 2048                  // per-bucket edge capacity (mean ~1023, sd ~32)

typedef __attribute__((ext_vector_type(8))) short bf16x8;
typedef __attribute__((ext_vector_type(4))) float f32x4;
typedef _Float16 hv2 __attribute__((ext_vector_type(2)));

// ---- DPP 16-lane row reduction (fusable v_add_f32_dpp form: old=0, bound_ctrl=1) ----
__device__ __forceinline__ float dpp4_redrow(float t) {
  t += __int_as_float(__builtin_amdgcn_update_dpp(0, __float_as_int(t), 0x111, 0xf, 0xf, true));
  t += __int_as_float(__builtin_amdgcn_update_dpp(0, __float_as_int(t), 0x112, 0xf, 0xf, true));
  t += __int_as_float(__builtin_amdgcn_update_dpp(0, __float_as_int(t), 0x114, 0xf, 0xf, true));
  t += __int_as_float(__builtin_amdgcn_update_dpp(0, __float_as_int(t), 0x118, 0xf, 0xf, true));
  return t;
}
// broadcast lane15 of each 16-lane group (BitMode: and=0x10, or=0x0F)
__device__ __forceinline__ float bcast15(float t) {
  return __int_as_float(__builtin_amdgcn_ds_swizzle(__float_as_int(t), 0x1F0));
}

__device__ __forceinline__ unsigned pkbf(float lo, float hi) {
  __hip_bfloat162 h = __float22bfloat162_rn(float2{lo, hi});  // x -> low 16 bits
  return *reinterpret_cast<unsigned*>(&h);
}

// ---------------- W transpose+convert: Wtb[c][k] bf16, c<128 = Wl, else Wr ----------------
__global__ __launch_bounds__(128) void prep_w(const float* __restrict__ Wl,
                                              const float* __restrict__ Wr,
                                              short* __restrict__ Wtb) {
  int c = blockIdx.x;           // 0..255
  int k = threadIdx.x;          // 0..127
  const float* W = (c < 128) ? Wl : Wr;
  float v = W[k * 128 + (c & 127)];
  Wtb[c * 128 + k] = (short)(pkbf(v, 0.f) & 0xFFFF);
}

// ---------------- GEMM (MFMA bf16): one x-tile stage -> BOTH xl and xr ----------------
__global__ __launch_bounds__(256) void gemm_xw(
    const float* __restrict__ x, const short* __restrict__ Wtb,
    _Float16* __restrict__ xlh, _Float16* __restrict__ xrh)
{
  __shared__ short xs[128 * 136];
  const int t = threadIdx.x;
  const int rowbase = blockIdx.x * 128;
#pragma unroll
  for (int i = 0; i < 16; ++i) {
    int fi = i * 256 + t;            // 4096 float4 per tile
    int row = fi >> 5, k4 = fi & 31;
    int ar = rowbase + row; if (ar >= NN) ar = NN - 1;
    float4 v = *(const float4*)(x + (size_t)ar * 128 + k4 * 4);
    uint2 p = { pkbf(v.x, v.y), pkbf(v.z, v.w) };
    *(uint2*)&xs[row * 136 + k4 * 4] = p;
  }
  __syncthreads();
  const int w = t >> 6, l = t & 63;
  const int lo16 = l & 15, hi = l >> 4;
  f32x4 accL[2][8], accR[2][8];
#pragma unroll
  for (int rf = 0; rf < 2; ++rf)
#pragma unroll
    for (int cf = 0; cf < 8; ++cf) {
      accL[rf][cf] = f32x4{0.f, 0.f, 0.f, 0.f};
      accR[rf][cf] = f32x4{0.f, 0.f, 0.f, 0.f};
    }

  const short* asrc0 = &xs[(w * 32 + lo16) * 136 + hi * 8];
  const short* asrc1 = asrc0 + 16 * 136;
#pragma unroll
  for (int ks = 0; ks < 4; ++ks) {
    bf16x8 a0 = *(const bf16x8*)(asrc0 + ks * 32);
    bf16x8 a1 = *(const bf16x8*)(asrc1 + ks * 32);
#pragma unroll
    for (int cf = 0; cf < 8; ++cf) {
      const short* bp = &Wtb[(cf * 16 + lo16) * 128 + ks * 32 + hi * 8];
      bf16x8 bL = *(const bf16x8*)bp;
      bf16x8 bR = *(const bf16x8*)(bp + 128 * 128);
      accL[0][cf] = __builtin_amdgcn_mfma_f32_16x16x32_bf16(a0, bL, accL[0][cf], 0, 0, 0);
      accL[1][cf] = __builtin_amdgcn_mfma_f32_16x16x32_bf16(a1, bL, accL[1][cf], 0, 0, 0);
      accR[0][cf] = __builtin_amdgcn_mfma_f32_16x16x32_bf16(a0, bR, accR[0][cf], 0, 0, 0);
      accR[1][cf] = __builtin_amdgcn_mfma_f32_16x16x32_bf16(a1, bR, accR[1][cf], 0, 0, 0);
    }
  }
  // D layout: col=l&15, row=(l>>4)*4+reg
#pragma unroll
  for (int rf = 0; rf < 2; ++rf)
#pragma unroll
    for (int cf = 0; cf < 8; ++cf)
#pragma unroll
      for (int r = 0; r < 4; ++r) {
        int row = rowbase + w * 32 + rf * 16 + hi * 4 + r;
        if (row < NN) {
          int col = cf * 16 + lo16;
          xlh[(size_t)row * 128 + col] = (_Float16)accL[rf][cf][r];
          xrh[(size_t)row * 128 + col] = (_Float16)accR[rf][cf][r];
        }
      }
}

// ---------------- CSR build: atomic-free two-level counting sort ----------------
__global__ __launch_bounds__(256) void hist_coarse(const int* __restrict__ ei,
                                                   int* __restrict__ H2) {
  __shared__ int h[NBUCK];
  int t = threadIdx.x, blk = blockIdx.x;
  for (int b = t; b < NBUCK; b += 256) h[b] = 0;
  __syncthreads();
  int e0 = blk * CHUNK;
  for (int i = t; i < CHUNK; i += 256) {
    int d = ei[EE + e0 + i];
    atomicAdd(&h[d >> 6], 1);      // LDS atomic
  }
  __syncthreads();
  for (int b = t; b < NBUCK; b += 256) H2[blk * NBUCK + b] = h[b];
}

// exclusive scan over bucket-major logical order (L = bucket*NBLK + blk)
__global__ __launch_bounds__(256) void scanA(const int* __restrict__ H2,
                                             int* __restrict__ PS, int* __restrict__ bsum) {
  __shared__ int tmp[256];
  int t = threadIdx.x;
  int base = blockIdx.x * 1024 + t * 4;
  int v[4], local = 0;
#pragma unroll
  for (int j = 0; j < 4; ++j) {
    int L = base + j;
    v[j] = (L < NTOT) ? H2[(L % NBLK) * NBUCK + (L / NBLK)] : 0;
    local += v[j];
  }
  tmp[t] = local; __syncthreads();
  for (int off = 1; off < 256; off <<= 1) {
    int xv = (t >= off) ? tmp[t - off] : 0; __syncthreads();
    tmp[t] += xv; __syncthreads();
  }
  int excl = tmp[t] - local;
#pragma unroll
  for (int j = 0; j < 4; ++j) { int L = base + j; if (L < NTOT) PS[L] = excl; excl += v[j]; }
  if (t == 255) bsum[blockIdx.x] = tmp[255];
}

__global__ void scanB(int* __restrict__ bsum) {
  __shared__ int tmp[256];
  int t = threadIdx.x;
  int v = (t < NSB) ? bsum[t] : 0;
  tmp[t] = v; __syncthreads();
  for (int off = 1; off < 256; off <<= 1) {
    int xv = (t >= off) ? tmp[t - off] : 0; __syncthreads();
    tmp[t] += xv; __syncthreads();
  }
  if (t < NSB) bsum[t] = tmp[t] - v;
}

// scatter into per-(bucket,block) sequential runs; pack src|fine<<16
__global__ __launch_bounds__(256) void scatter_coarse(const int* __restrict__ ei,
                                                      const int* __restrict__ PS,
                                                      const int* __restrict__ bsum,
                                                      int* __restrict__ ec) {
  __shared__ int colbase[NBUCK];
  __shared__ int cur[NBUCK];
  int t = threadIdx.x, blk = blockIdx.x;
  for (int b = t; b < NBUCK; b += 256) {
    int L = b * NBLK + blk;
    colbase[b] = PS[L] + bsum[L >> 10];
    cur[b] = 0;
  }
  __syncthreads();
  int e0 = blk * CHUNK;
  for (int i = t; i < CHUNK; i += 256) {
    int d = ei[EE + e0 + i], s = ei[e0 + i];
    int b = d >> 6;
    int r = atomicAdd(&cur[b], 1);  // LDS atomic
    ec[colbase[b] + r] = s | ((d & 63) << 16);
  }
}

// per-bucket fine sort (64 nodes), inject self-loops, emit rs + coalesced csr
__global__ __launch_bounds__(256) void fine_sort(const int* __restrict__ PS,
                                                 const int* __restrict__ bsum,
                                                 const int* __restrict__ ec,
                                                 int* __restrict__ rs, int* __restrict__ csr) {
  __shared__ int lbuf[ECAP];
  __shared__ int outb[ECAP + 64];
  __shared__ int fh[64], sexcl[65], cur2[64];
  int t = threadIdx.x, b = blockIdx.x;
  int L0 = b * NBLK;
  int start = PS[L0] + bsum[L0 >> 10];
  int end;
  if (b + 1 < NBUCK) { int L1 = (b + 1) * NBLK; end = PS[L1] + bsum[L1 >> 10]; }
  else end = EE;
  int node0 = b << 6;
  int nl = NN - node0; if (nl > 64) nl = 64;
  int cnt = end - start; if (cnt > ECAP) cnt = ECAP;
  if (t < 64) { fh[t] = 0; cur2[t] = 0; }
  __syncthreads();
  for (int i = t; i < cnt; i += 256) {
    int p = ec[start + i];
    lbuf[i] = p;
    atomicAdd(&fh[(p >> 16) & 63], 1);
  }
  __syncthreads();
  if (t < 64) {   // wave 0: inclusive shfl-scan of 64 bins (+1 self-loop per live node)
    int val = fh[t] + (t < nl ? 1 : 0);
    int w = val;
    for (int off = 1; off < 64; off <<= 1) {
      int u = __shfl_up(w, off);
      if (t >= off) w += u;
    }
    sexcl[t] = w - val;
    if (t == 63) sexcl[64] = w;
  }
  __syncthreads();
  int base = start + node0;   // node0 == number of self-loops in earlier buckets
  if (t <= nl) rs[node0 + t] = base + sexcl[t];
  if (t < nl) {
    int r = atomicAdd(&cur2[t], 1);
    outb[sexcl[t] + r] = node0 + t;              // self-loop src = node itself
  }
  for (int i = t; i < cnt; i += 256) {
    int p = lbuf[i];
    int f = (p >> 16) & 63;
    int r = atomicAdd(&cur2[f], 1);
    outb[sexcl[f] + r] = p & 0xFFFF;
  }
  __syncthreads();
  int tot = cnt + nl;
  for (int i = t; i < tot; i += 256) csr[base + i] = outb[i];
}

// ---------------- main aggregation: one wave per node, stage-split 8-edge batches ----------------
__global__ __launch_bounds__(256) void gat_agg(
    const unsigned* __restrict__ xlu, const unsigned* __restrict__ xru,
    const int* __restrict__ rs, const int* __restrict__ csr,
    const float* __restrict__ att, const float* __restrict__ bias,
    float* __restrict__ outn)
{
  int wid = threadIdx.x >> 6, lane = threadIdx.x & 63;
  int n = blockIdx.x * 4 + wid;
  if (n >= NN) return;
  hv2 xr2 = __builtin_bit_cast(hv2, xru[n * 64 + lane]);
  float2 at2 = ((const float2*)att)[lane];
  const float LOG2E = 1.4426950408889634f;
  hv2 att2;
  att2.x = (_Float16)(at2.x * LOG2E);
  att2.y = (_Float16)(at2.y * LOG2E);
  float s = 0.f, a0 = 0.f, a1 = 0.f;

  int jbeg = rs[n], jend = rs[n + 1];
  for (int j0 = jbeg; j0 < jend; j0 += 64) {
    int cnt = jend - j0; if (cnt > 64) cnt = 64;
    int sj = csr[j0 + (lane < cnt ? lane : cnt - 1)];
    int base = 0;
    for (; base + 8 <= cnt; base += 8) {
      unsigned wv[8];
#pragma unroll
      for (int i = 0; i < 8; ++i)
        wv[i] = xlu[__builtin_amdgcn_readlane(sj, base + i) * 64 + lane];
      // stage 1: 8 independent logit chains (DS broadcasts overlap)
      float tb[8];
#pragma unroll
      for (int i = 0; i < 8; ++i) {
        hv2 v = __builtin_bit_cast(hv2, wv[i]);
        hv2 y = v + xr2;
        hv2 lr = __builtin_elementwise_max(y, y * (_Float16)0.2f);
        float td = __builtin_amdgcn_fdot2(lr, att2, 0.f, false);
        tb[i] = bcast15(dpp4_redrow(td));
      }
      // stage 2: 8 exps back-to-back (trans pipe pipelines)
      float p[8];
#pragma unroll
      for (int i = 0; i < 8; ++i) p[i] = __builtin_amdgcn_exp2f(tb[i]);
      // stage 3: accumulate
#pragma unroll
      for (int i = 0; i < 8; ++i) {
        hv2 v = __builtin_bit_cast(hv2, wv[i]);
        s += p[i];
        a0 = fmaf(p[i], (float)v.x, a0);
        a1 = fmaf(p[i], (float)v.y, a1);
      }
    }
    for (; base < cnt; ++base) {
      unsigned w0 = xlu[__builtin_amdgcn_readlane(sj, base) * 64 + lane];
      hv2 va = __builtin_bit_cast(hv2, w0);
      hv2 ya = va + xr2;
      hv2 la = __builtin_elementwise_max(ya, ya * (_Float16)0.2f);
      float t = __builtin_amdgcn_fdot2(la, att2, 0.f, false);
      float p = __builtin_amdgcn_exp2f(bcast15(dpp4_redrow(t)));
      s += p;
      a0 = fmaf(p, (float)va.x, a0); a1 = fmaf(p, (float)va.y, a1);
    }
  }
  float inv = 1.f / s;
  float2 bi = ((const float2*)bias)[lane];
  float2 o;
  o.x = fmaxf(fmaf(a0, inv, bi.x), 0.f);
  o.y = fmaxf(fmaf(a1, inv, bi.y), 0.f);
  ((float2*)outn)[n * 64 + lane] = o;
}

// ---------------- pooling ----------------
__global__ __launch_bounds__(128) void pool_max(const float* __restrict__ outn,
                                                const int* __restrict__ batch,
                                                unsigned int* __restrict__ pooled) {
  int c = threadIdx.x;
  int n0 = blockIdx.x * 128;
  int nend = n0 + 128; if (nend > NN) nend = NN;
  int curg = batch[n0];
  float mx = 0.f;
#pragma unroll 4
  for (int n = n0; n < nend; ++n) {
    int g = batch[n];
    if (g != curg) {
      atomicMax(&pooled[curg * HC + c], __float_as_uint(mx));
      mx = 0.f; curg = g;
    }
    mx = fmaxf(mx, outn[(size_t)n * HC + c]);
  }
  atomicMax(&pooled[curg * HC + c], __float_as_uint(mx));
}

// ---------------- MLP head ----------------
__global__ __launch_bounds__(128) void mlp_out(const unsigned int* __restrict__ pooled,
                                               const float* __restrict__ W,
                                               const float* __restrict__ b,
                                               float* __restrict__ out) {
  __shared__ float p[128];
  int g = blockIdx.x, j = threadIdx.x;
  p[j] = __uint_as_float(pooled[g * HC + j]);
  __syncthreads();
  float acc = b[j];
#pragma unroll 8
  for (int k = 0; k < 128; ++k) acc = fmaf(p[k], W[k * 128 + j], acc);
  out[g * HC + j] = fmaxf(acc, 0.f);
}

extern "C" void kernel_launch(void* const* d_in, const int* in_sizes, int n_in,
                              void* d_out, int out_size, void* d_ws, size_t ws_size,
                              hipStream_t stream) {
  const float* x    = (const float*)d_in[0];
  const int*   ei   = (const int*)d_in[1];
  const int*   batch= (const int*)d_in[2];
  const float* Wl   = (const float*)d_in[4];
  const float* Wr   = (const float*)d_in[5];
  const float* att  = (const float*)d_in[6];
  const float* bias = (const float*)d_in[7];
  const float* Wm   = (const float*)d_in[8];
  const float* bm   = (const float*)d_in[9];

  char* ws = (char*)d_ws;
  size_t off = 0;
  auto alloc = [&](size_t bytes) { void* p = ws + off; off += (bytes + 255) & ~size_t(255); return p; };
  unsigned* xlu  = (unsigned*)alloc((size_t)NN * 64 * 4);   // f16-packed xl (12.8 MB)
  unsigned* xru  = (unsigned*)alloc((size_t)NN * 64 * 4);   // f16-packed xr (12.8 MB)
  float* outn    = (float*)alloc((size_t)NN * HC * 4);
  int*   rs      = (int*)alloc((size_t)(NN + 1) * 4);
  int*   csr     = (int*)alloc((size_t)(EE + NN) * 4);
  int*   bsum    = (int*)alloc(NSB * 4);
  short* Wtb     = (short*)alloc((size_t)256 * 128 * 2);    // bf16 W^T [col][k]
  unsigned int* pooled = (unsigned int*)alloc((size_t)GG * HC * 4);
  // scratch aliased into outn (dead before gat_agg writes outn):
  int* ec = (int*)outn;                                      // 3.2 MB coarse-sorted edges
  int* H2 = (int*)((char*)outn + (size_t)4 * 1024 * 1024);   // 800 KB count matrix
  int* PS = (int*)((char*)outn + (size_t)6 * 1024 * 1024);   // 800 KB scanned positions

  (void)hipMemsetAsync(pooled, 0, (size_t)GG * HC * 4, stream);

  prep_w<<<256, 128, 0, stream>>>(Wl, Wr, Wtb);
  gemm_xw<<<(NN + 127) / 128, 256, 0, stream>>>(x, Wtb, (_Float16*)xlu, (_Float16*)xru);
  hist_coarse<<<NBLK, 256, 0, stream>>>(ei, H2);
  scanA<<<NSB, 256, 0, stream>>>(H2, PS, bsum);
  scanB<<<1, 256, 0, stream>>>(bsum);
  scatter_coarse<<<NBLK, 256, 0, stream>>>(ei, PS, bsum, ec);
  fine_sort<<<NBUCK, 256, 0, stream>>>(PS, bsum, ec, rs, csr);
  gat_agg<<<NN / 4, 256, 0, stream>>>(xlu, xru, rs, csr, att, bias, outn);
  pool_max<<<(NN + 127) / 128, 128, 0, stream>>>(outn, batch, pooled);
  mlp_out<<<GG, 128, 0, stream>>>(pooled, Wm, bm, (float*)d_out);
}